// Round 1
// 238.516 us; speedup vs baseline: 1.2728x; 1.2728x over previous
//
#include <hip/hip_runtime.h>
#include <math.h>

// ---------------------------------------------------------------------------
#define B_ROWS   8192
#define NZ       100
#define NC       2
#define H1       256
#define H2       64
#define FEATN    8192
#define FDIM     1024
#define RROWS    16            // rows per k_main block = MFMA M
#define NTILE    (FEATN / 16)  // 512 16-col MFMA tiles
#define A1ROWS   16
#define A1BLKS   (B_ROWS / A1ROWS)   // 512
#define CONVBLKS 256                 // w3 conversion blocks fused into k_a1
#define A2BLKS   (B_ROWS / 4)        // 2048

typedef __attribute__((ext_vector_type(8))) short short8;
typedef __attribute__((ext_vector_type(4))) float f32x4;

// ---------------------------------------------------------------------------
// JAX threefry2x32, partitionable, key=(0,42), counter=(0, flat)
__device__ __forceinline__ unsigned rotl32(unsigned v, int r) {
    return (v << r) | (v >> (32 - r));
}
__device__ __forceinline__ unsigned threefry_bits(unsigned lo) {
    const unsigned ks0 = 0u, ks1 = 42u, ks2 = 0x1BD11BDAu ^ 42u;
    unsigned x0 = 0u + ks0;
    unsigned x1 = lo + ks1;
#define TF_R4(a,b,c,d) \
    x0 += x1; x1 = rotl32(x1,a); x1 ^= x0; \
    x0 += x1; x1 = rotl32(x1,b); x1 ^= x0; \
    x0 += x1; x1 = rotl32(x1,c); x1 ^= x0; \
    x0 += x1; x1 = rotl32(x1,d); x1 ^= x0;
    TF_R4(13,15,26,6);  x0 += ks1; x1 += ks2 + 1u;
    TF_R4(17,29,16,24); x0 += ks2; x1 += ks0 + 2u;
    TF_R4(13,15,26,6);  x0 += ks0; x1 += ks1 + 3u;
    TF_R4(17,29,16,24); x0 += ks1; x1 += ks2 + 4u;
    TF_R4(13,15,26,6);  x0 += ks2; x1 += ks0 + 5u;
#undef TF_R4
    return x0 ^ x1;
}
__device__ __forceinline__ float gumbel_g(unsigned flat) {
    unsigned bits = threefry_bits(flat);
    float u  = __uint_as_float((bits >> 9) | 0x3f800000u) - 1.0f;
    float U  = 0.001f * u;
    float t1 = U + 0.001f;
    float L1 = (float)log((double)t1);
    float A  = 0.001f - L1;
    float L2 = (float)log((double)A);
    return -L2;
}

// float -> bf16 RNE
__device__ __forceinline__ unsigned short f2bf(float x) {
    unsigned u = __float_as_uint(x);
    u += 0x7fffu + ((u >> 16) & 1u);
    return (unsigned short)(u >> 16);
}
// order-preserving float -> u32
__device__ __forceinline__ unsigned fmono(float x) {
    unsigned b = __float_as_uint(x);
    return (b & 0x80000000u) ? ~b : (b | 0x80000000u);
}

// 16-lane (within-row) max reduce via DPP on the VALU pipe — avoids the
// DS-pipe serialization that 16x shfl_xor per tile would cost.
__device__ __forceinline__ float dppmax16(float v) {
    int y;
    y = __builtin_amdgcn_update_dpp(0, __float_as_int(v), 0xB1,  0xF, 0xF, true); // quad_perm [1,0,3,2]
    v = fmaxf(v, __int_as_float(y));
    y = __builtin_amdgcn_update_dpp(0, __float_as_int(v), 0x4E,  0xF, 0xF, true); // quad_perm [2,3,0,1]
    v = fmaxf(v, __int_as_float(y));
    y = __builtin_amdgcn_update_dpp(0, __float_as_int(v), 0x141, 0xF, 0xF, true); // row_half_mirror
    v = fmaxf(v, __int_as_float(y));
    y = __builtin_amdgcn_update_dpp(0, __float_as_int(v), 0x140, 0xF, 0xF, true); // row_mirror
    v = fmaxf(v, __int_as_float(y));
    return v;
}

// ---------------------------------------------------------------------------
// K1: blocks [0,A1BLKS): a1 = concat(x,y)@W1 + b1 (fp64) + BN partials.
//     blocks [A1BLKS,..): convert W3 -> bf16 MFMA-B-fragment layout + max|W3|.
__global__ __launch_bounds__(256) void k_a1(
    const float* __restrict__ x, const float* __restrict__ y,
    const float* __restrict__ W1, const float* __restrict__ b1,
    const float* __restrict__ W3,
    float* __restrict__ a1, double* __restrict__ p1, double* __restrict__ p2,
    unsigned short* __restrict__ w3s, float* __restrict__ maxw)
{
    const int t = threadIdx.x;

    if (blockIdx.x >= A1BLKS) {
        const int job  = (blockIdx.x - A1BLKS) * 256 + t;   // 0..65535
        const int T    = job >> 7;
        const int rem  = job & 127;
        const int kh   = rem >> 6;
        const int l    = rem & 63;
        const int quad = l >> 4, col = l & 15;
        const float* src = W3 + (size_t)(kh * 32 + quad * 8) * FEATN + T * 16 + col;
        unsigned short v[8];
        float mx = 0.0f;
#pragma unroll
        for (int jj = 0; jj < 8; ++jj) {
            float xv = src[(size_t)jj * FEATN];
            mx = fmaxf(mx, fabsf(xv));
            v[jj] = f2bf(xv);
        }
        uint4 o;
        o.x = (unsigned)v[0] | ((unsigned)v[1] << 16);
        o.y = (unsigned)v[2] | ((unsigned)v[3] << 16);
        o.z = (unsigned)v[4] | ((unsigned)v[5] << 16);
        o.w = (unsigned)v[6] | ((unsigned)v[7] << 16);
        ((uint4*)w3s)[job] = o;
#pragma unroll
        for (int off = 32; off; off >>= 1) mx = fmaxf(mx, __shfl_xor(mx, off));
        __shared__ float wred[4];
        if ((t & 63) == 0) wred[t >> 6] = mx;
        __syncthreads();
        if (t == 0) {
            float m = fmaxf(fmaxf(wred[0], wred[1]), fmaxf(wred[2], wred[3]));
            atomicMax((unsigned*)maxw, __float_as_uint(m));
        }
        return;
    }

    const int j  = t;
    const int b0 = blockIdx.x * A1ROWS;

    // Stage the activation tile in LDS: the inner loop previously issued
    // ~1600 same-address scalar global loads per wave (VMEM-issue-bound).
    __shared__ float xs[A1ROWS * NZ];   // 6.4 KB
    __shared__ float ys[A1ROWS * NC];
    for (int q = t; q < A1ROWS * NZ; q += 256) xs[q] = x[(size_t)b0 * NZ + q];
    if (t < A1ROWS * NC) ys[t] = y[b0 * NC + t];
    __syncthreads();

    double acc[A1ROWS];
#pragma unroll
    for (int r = 0; r < A1ROWS; ++r) acc[r] = 0.0;
    for (int i = 0; i < NZ; ++i) {
        float w = W1[i * H1 + j];
#pragma unroll
        for (int r = 0; r < A1ROWS; ++r)
            acc[r] += (double)xs[r * NZ + i] * (double)w;
    }
#pragma unroll
    for (int i = 0; i < NC; ++i) {
        float w = W1[(NZ + i) * H1 + j];
#pragma unroll
        for (int r = 0; r < A1ROWS; ++r)
            acc[r] += (double)ys[r * NC + i] * (double)w;
    }
    double bb = (double)b1[j];
    double s = 0.0, s2 = 0.0;
#pragma unroll
    for (int r = 0; r < A1ROWS; ++r) {
        float v = (float)(acc[r] + bb);
        a1[(b0 + r) * H1 + j] = v;
        double dv = (double)v;
        s += dv; s2 += dv * dv;
    }
    p1[blockIdx.x * H1 + j] = s;
    p2[blockIdx.x * H1 + j] = s2;
}

// ---------------------------------------------------------------------------
__global__ __launch_bounds__(256) void k_stats2(
    const double* __restrict__ p1, const double* __restrict__ p2,
    int nprt, int ncol,
    const float* __restrict__ gamma, const float* __restrict__ beta,
    float* __restrict__ scale, float* __restrict__ shift)
{
    const int j = blockIdx.x, t = threadIdx.x;
    double s = 0.0, s2 = 0.0;
    for (int g = t; g < nprt; g += 256) {
        s  += p1[(size_t)g * ncol + j];
        s2 += p2[(size_t)g * ncol + j];
    }
#pragma unroll
    for (int off = 32; off; off >>= 1) {
        s  += __shfl_xor(s, off);
        s2 += __shfl_xor(s2, off);
    }
    __shared__ double ws1[4], ws2[4];
    if ((t & 63) == 0) { ws1[t >> 6] = s; ws2[t >> 6] = s2; }
    __syncthreads();
    if (t == 0) {
        s  = (ws1[0] + ws1[1]) + (ws1[2] + ws1[3]);
        s2 = (ws2[0] + ws2[1]) + (ws2[2] + ws2[3]);
        double mean = s * (1.0 / B_ROWS);
        double var  = s2 * (1.0 / B_ROWS) - mean * mean;
        double rstd = 1.0 / sqrt(var + 1e-5);
        double sc   = (double)gamma[j] * rstd;
        scale[j] = (float)sc;
        shift[j] = (float)((double)beta[j] - mean * sc);
    }
}

// ---------------------------------------------------------------------------
__global__ __launch_bounds__(256) void k_a2(
    const float* __restrict__ a1,
    const float* __restrict__ sc1, const float* __restrict__ sh1,
    const float* __restrict__ W2, const float* __restrict__ b2,
    float* __restrict__ a2, double* __restrict__ p1, double* __restrict__ p2)
{
    const int t  = threadIdx.x;
    const int k  = t & 63;
    const int rr = t >> 6;
    const int b  = blockIdx.x * 4 + rr;
    double acc = 0.0;
    for (int j = 0; j < H1; ++j) {
        float h = fmaxf(fmaf(a1[b * H1 + j], sc1[j], sh1[j]), 0.0f);
        acc += (double)h * (double)W2[j * H2 + k];
    }
    float v = (float)(acc + (double)b2[k]);
    a2[b * H2 + k] = v;

    __shared__ double ls[256], ls2[256];
    ls[t]  = (double)v;
    ls2[t] = (double)v * (double)v;
    __syncthreads();
    if (t < 64) {
        double s  = (ls[t]  + ls[t + 64])  + (ls[t + 128]  + ls[t + 192]);
        double s2 = (ls2[t] + ls2[t + 64]) + (ls2[t + 128] + ls2[t + 192]);
        p1[blockIdx.x * H2 + t] = s;
        p2[blockIdx.x * H2 + t] = s2;
    }
}

// ---------------------------------------------------------------------------
// K5: pass A = bf16 MFMA bounds at PER-16-COL-TILE granularity (DPP 16-lane
// reduce, fineT[512][17] LDS); parallel threshold phase (all 512 threads);
// worklist of (row, tile16) cells; pass B = exact fp32, 4 KB/cell (one 64-B
// line per W3 row) instead of 32 KB/cell at the old 128-col granularity.
__global__ __launch_bounds__(512)
__attribute__((amdgpu_waves_per_eu(4, 4)))
void k_main(
    const float* __restrict__ a2,
    const float* __restrict__ sc2, const float* __restrict__ sh2,
    const float* __restrict__ W3, const float* __restrict__ b3,
    const unsigned short* __restrict__ w3s, const float* __restrict__ maxw,
    const float* __restrict__ codebook, float* __restrict__ out)
{
    const int t    = threadIdx.x;
    const int wv   = t >> 6;           // wave 0..7
    const int lane = t & 63;
    const int quad = lane >> 4, col = lane & 15;
    const int b0   = blockIdx.x * RROWS;

    __shared__ __align__(16) float h2T[64][17];     // [j][r], padded
    __shared__ float fineT[NTILE][17];              // per-(tile16, row) bf16 max
    __shared__ float thrS[RROWS];
    __shared__ unsigned long long best[RROWS];
    __shared__ unsigned short wl[RROWS * NTILE];    // sized at true max: no overflow
    __shared__ int wlN;
    __shared__ int rowInd[RROWS];
    __shared__ float maxwS;

    if (t == 0) { maxwS = maxw[0]; wlN = 0; }
    for (int q = t; q < RROWS * 64; q += 512) {
        int j = q >> 4, r = q & 15;
        float v = a2[(b0 + r) * H2 + j];
        h2T[j][r] = fmaxf(fmaf(v, sc2[j], sh2[j]), 0.0f);
    }
    __syncthreads();

    // A fragments (bf16): A[m=col][k=quad*8+jj], k-halves 0/1
    short8 aF0, aF1;
#pragma unroll
    for (int jj = 0; jj < 8; ++jj) {
        aF0[jj] = (short)f2bf(h2T[quad * 8 + jj][col]);
        aF1[jj] = (short)f2bf(h2T[32 + quad * 8 + jj][col]);
    }

    // ---- Pass A: 8 segments x 8 tiles; 16 tile-loads batched per segment;
    //      per-tile 16-lane DPP max -> fineT[T][row] ----
    {
        const uint4* wp  = (const uint4*)w3s + (size_t)wv * 8192 + lane;
        const float* b3p = b3 + wv * 1024 + col;
        for (int s = 0; s < 8; ++s) {
            uint4 c[8], d[8];
            float bb[8];
#pragma unroll
            for (int u = 0; u < 8; ++u) {
                c[u]  = wp[u * 128];
                d[u]  = wp[u * 128 + 64];
                bb[u] = b3p[u * 16];
            }
#pragma unroll
            for (int u = 0; u < 8; ++u) {
                f32x4 acc = {bb[u], bb[u], bb[u], bb[u]};
                acc = __builtin_amdgcn_mfma_f32_16x16x32_bf16(
                          aF0, *(const short8*)&c[u], acc, 0, 0, 0);
                acc = __builtin_amdgcn_mfma_f32_16x16x32_bf16(
                          aF1, *(const short8*)&d[u], acc, 0, 0, 0);
                float m0 = dppmax16(acc[0]);
                float m1 = dppmax16(acc[1]);
                float m2 = dppmax16(acc[2]);
                float m3 = dppmax16(acc[3]);
                if (col == 0) {
                    const int T = (wv * 8 + s) * 8 + u;
                    fineT[T][quad * 4 + 0] = m0;
                    fineT[T][quad * 4 + 1] = m1;
                    fineT[T][quad * 4 + 2] = m2;
                    fineT[T][quad * 4 + 3] = m3;
                }
            }
            wp += 1024; b3p += 128;
        }
    }
    __syncthreads();

    // ---- Thresholds: all 512 threads; row = t>>5, 32 lanes per row ----
    {
        const int r = t >> 5, cc = t & 31;
        float s = fabsf(h2T[2 * cc][r]) + fabsf(h2T[2 * cc + 1][r]);
        float gmv = -1e30f;
#pragma unroll
        for (int k = 0; k < 16; ++k) gmv = fmaxf(gmv, fineT[cc + 32 * k][r]);
#pragma unroll
        for (int off = 1; off < 32; off <<= 1) {
            s   += __shfl_xor(s, off);
            gmv  = fmaxf(gmv, __shfl_xor(gmv, off));
        }
        if (cc == 0) {
            float e = s * maxwS * (1.0f / 256.0f);   // |dlogit| <= S*maxW*2^-8
            thrS[r] = gmv - (0.1068f + e + 1e-3f);
            best[r] = 0ull;
        }
    }
    __syncthreads();

    // ---- Worklist of qualifying (row, tile16) cells ----
    {
        const int r = t >> 5, cc = t & 31;
        const float th = thrS[r];
#pragma unroll
        for (int k = 0; k < 16; ++k) {
            const int T = cc + 32 * k;
            if (fineT[T][r] >= th) {
                int idx = atomicAdd(&wlN, 1);
                wl[idx] = (unsigned short)((r << 9) | T);
            }
        }
    }
    __syncthreads();

    // ---- Pass B: wave handles 4 cells (16 lanes each); exact fp32 ----
    {
        const int n = wlN;
        const int g = lane >> 4;       // cell slot within wave
        for (int i = wv * 4; i < n; i += 32) {
            const int  ci  = i + g;
            const bool act = (ci < n);
            const int  e   = act ? wl[ci] : 0;
            const int  r   = e >> 9;
            const int  T   = e & 511;
            const int  f   = T * 16 + col;
            float acc = b3[f];
            const float* wcol = W3 + f;
#pragma unroll 8
            for (int j = 0; j < 64; ++j) {
                acc = fmaf(h2T[j][r], *wcol, acc);
                wcol += FEATN;
            }
            if (act && acc >= thrS[r]) {
                float sc = acc + gumbel_g((unsigned)(b0 + r) * (unsigned)FEATN + (unsigned)f);
                unsigned long long pk = ((unsigned long long)fmono(sc) << 32)
                                      | (unsigned)(FEATN - 1 - f);
                atomicMax(&best[r], pk);
            }
        }
    }
    __syncthreads();
    if (t < RROWS) {
        rowInd[t] = (FEATN - 1 - (int)(best[t] & 0xFFFFFFFFull)) & (FEATN - 1);
    }
    __syncthreads();

    // ---- out[b,:] = codebook[ind,:] ----
    {
        const int rr = t >> 8, tt = t & 255;
        for (int rp = 0; rp < RROWS / 2; ++rp) {
            const int r = rp * 2 + rr;
            const int ind = rowInd[r];
            const float4* src = (const float4*)(codebook + (size_t)ind * FDIM);
            float4*       dst = (float4*)(out + (size_t)(b0 + r) * FDIM);
            dst[tt] = src[tt];
        }
    }
}

// ---------------------------------------------------------------------------
extern "C" void kernel_launch(void* const* d_in, const int* in_sizes, int n_in,
                              void* d_out, int out_size, void* d_ws, size_t ws_size,
                              hipStream_t stream)
{
    const float* x   = (const float*)d_in[0];
    const float* y   = (const float*)d_in[1];
    const float* W1  = (const float*)d_in[2];
    const float* b1  = (const float*)d_in[3];
    const float* g1  = (const float*)d_in[4];
    const float* be1 = (const float*)d_in[5];
    const float* W2  = (const float*)d_in[6];
    const float* b2  = (const float*)d_in[7];
    const float* g2  = (const float*)d_in[8];
    const float* be2 = (const float*)d_in[9];
    const float* W3  = (const float*)d_in[10];
    const float* b3  = (const float*)d_in[11];
    const float* cb  = (const float*)d_in[12];
    float* out = (float*)d_out;

    float* ws  = (float*)d_ws;
    float* a1  = ws;                          // 8 MB
    float* a2  = a1 + B_ROWS * H1;            // 2 MB
    float* sc1 = a2 + B_ROWS * H2;
    float* sh1 = sc1 + H1;
    float* sc2 = sh1 + H1;
    float* sh2 = sc2 + H2;
    double* p1 = (double*)(sh2 + H2);         // 1 MB
    double* p2 = p1 + A2BLKS * H2;            // 1 MB
    unsigned short* w3s = (unsigned short*)(p2 + A2BLKS * H2);  // 1 MB bf16
    float* maxw = (float*)(w3s + NTILE * 2 * 64 * 8);           // 1 f32

    hipMemsetAsync(maxw, 0, 4, stream);
    k_a1    <<<A1BLKS + CONVBLKS, 256, 0, stream>>>(x, y, W1, b1, W3,
                                                    a1, p1, p2, w3s, maxw);
    k_stats2<<<H1, 256, 0, stream>>>(p1, p2, A1BLKS, H1, g1, be1, sc1, sh1);
    k_a2    <<<A2BLKS, 256, 0, stream>>>(a1, sc1, sh1, W2, b2, a2, p1, p2);
    k_stats2<<<H2, 256, 0, stream>>>(p1, p2, A2BLKS, H2, g2, be2, sc2, sh2);
    k_main  <<<B_ROWS / RROWS, 512, 0, stream>>>(a2, sc2, sh2, W3, b3,
                                                 w3s, maxw, cb, out);
}

// Round 2
// 214.521 us; speedup vs baseline: 1.4152x; 1.1119x over previous
//
#include <hip/hip_runtime.h>
#include <math.h>

// ---------------------------------------------------------------------------
#define B_ROWS   8192
#define NZ       100
#define NC       2
#define H1       256
#define H2       64
#define FEATN    8192
#define FDIM     1024
#define RROWS    16            // rows per k_main block = MFMA M
#define NTILE    (FEATN / 16)  // 512 16-col MFMA tiles
#define A1ROWS   16
#define A1BLKS   (B_ROWS / A1ROWS)   // 512
#define CONVBLKS 256                 // w3 conversion blocks fused into k_a1
#define A2ROWS   16
#define A2BLKS   (B_ROWS / A2ROWS)   // 512

typedef __attribute__((ext_vector_type(8))) short short8;
typedef __attribute__((ext_vector_type(4))) float f32x4;

// ---------------------------------------------------------------------------
// JAX threefry2x32, partitionable, key=(0,42), counter=(0, flat)
__device__ __forceinline__ unsigned rotl32(unsigned v, int r) {
    return (v << r) | (v >> (32 - r));
}
__device__ __forceinline__ unsigned threefry_bits(unsigned lo) {
    const unsigned ks0 = 0u, ks1 = 42u, ks2 = 0x1BD11BDAu ^ 42u;
    unsigned x0 = 0u + ks0;
    unsigned x1 = lo + ks1;
#define TF_R4(a,b,c,d) \
    x0 += x1; x1 = rotl32(x1,a); x1 ^= x0; \
    x0 += x1; x1 = rotl32(x1,b); x1 ^= x0; \
    x0 += x1; x1 = rotl32(x1,c); x1 ^= x0; \
    x0 += x1; x1 = rotl32(x1,d); x1 ^= x0;
    TF_R4(13,15,26,6);  x0 += ks1; x1 += ks2 + 1u;
    TF_R4(17,29,16,24); x0 += ks2; x1 += ks0 + 2u;
    TF_R4(13,15,26,6);  x0 += ks0; x1 += ks1 + 3u;
    TF_R4(17,29,16,24); x0 += ks1; x1 += ks2 + 4u;
    TF_R4(13,15,26,6);  x0 += ks2; x1 += ks0 + 5u;
#undef TF_R4
    return x0 ^ x1;
}
__device__ __forceinline__ float gumbel_g(unsigned flat) {
    unsigned bits = threefry_bits(flat);
    float u  = __uint_as_float((bits >> 9) | 0x3f800000u) - 1.0f;
    float U  = 0.001f * u;
    float t1 = U + 0.001f;
    float L1 = (float)log((double)t1);
    float A  = 0.001f - L1;
    float L2 = (float)log((double)A);
    return -L2;
}

// float -> bf16 RNE
__device__ __forceinline__ unsigned short f2bf(float x) {
    unsigned u = __float_as_uint(x);
    u += 0x7fffu + ((u >> 16) & 1u);
    return (unsigned short)(u >> 16);
}
// order-preserving float -> u32
__device__ __forceinline__ unsigned fmono(float x) {
    unsigned b = __float_as_uint(x);
    return (b & 0x80000000u) ? ~b : (b | 0x80000000u);
}

// ---------------------------------------------------------------------------
// K1: blocks [0,A1BLKS): a1 = concat(x,y)@W1 + b1 (fp64) + BN partials.
//     blocks [A1BLKS,..): convert W3 -> bf16 MFMA-B-fragment layout + max|W3|.
__global__ __launch_bounds__(256) void k_a1(
    const float* __restrict__ x, const float* __restrict__ y,
    const float* __restrict__ W1, const float* __restrict__ b1,
    const float* __restrict__ W3,
    float* __restrict__ a1, double* __restrict__ p1, double* __restrict__ p2,
    unsigned short* __restrict__ w3s, float* __restrict__ maxw)
{
    const int t = threadIdx.x;

    if (blockIdx.x >= A1BLKS) {
        const int job  = (blockIdx.x - A1BLKS) * 256 + t;   // 0..65535
        const int T    = job >> 7;
        const int rem  = job & 127;
        const int kh   = rem >> 6;
        const int l    = rem & 63;
        const int quad = l >> 4, col = l & 15;
        const float* src = W3 + (size_t)(kh * 32 + quad * 8) * FEATN + T * 16 + col;
        unsigned short v[8];
        float mx = 0.0f;
#pragma unroll
        for (int jj = 0; jj < 8; ++jj) {
            float xv = src[(size_t)jj * FEATN];
            mx = fmaxf(mx, fabsf(xv));
            v[jj] = f2bf(xv);
        }
        uint4 o;
        o.x = (unsigned)v[0] | ((unsigned)v[1] << 16);
        o.y = (unsigned)v[2] | ((unsigned)v[3] << 16);
        o.z = (unsigned)v[4] | ((unsigned)v[5] << 16);
        o.w = (unsigned)v[6] | ((unsigned)v[7] << 16);
        ((uint4*)w3s)[job] = o;
#pragma unroll
        for (int off = 32; off; off >>= 1) mx = fmaxf(mx, __shfl_xor(mx, off));
        __shared__ float wred[4];
        if ((t & 63) == 0) wred[t >> 6] = mx;
        __syncthreads();
        if (t == 0) {
            float m = fmaxf(fmaxf(wred[0], wred[1]), fmaxf(wred[2], wred[3]));
            atomicMax((unsigned*)maxw, __float_as_uint(m));
        }
        return;
    }

    const int j  = t;
    const int b0 = blockIdx.x * A1ROWS;

    // Transposed LDS x-tile: xs[i][r] so the 16 row-values at fixed i are one
    // contiguous 64B line -> 4x ds_read_b128 broadcast per i (vs 16x b32).
    __shared__ __align__(16) float xs[NZ][16];   // 6.4 KB
    __shared__ __align__(16) float ys[NC][16];
    for (int q = t; q < A1ROWS * NZ; q += 256) {
        int r = q / NZ, i = q - r * NZ;
        xs[i][r] = x[(size_t)b0 * NZ + q];
    }
    if (t < A1ROWS * NC) {
        int r = t >> 1, i = t & 1;
        ys[i][r] = y[b0 * NC + t];
    }
    __syncthreads();

    double acc[A1ROWS];
#pragma unroll
    for (int r = 0; r < A1ROWS; ++r) acc[r] = 0.0;
    for (int i = 0; i < NZ; ++i) {
        double wd = (double)W1[i * H1 + j];
        const float4 x0 = *(const float4*)&xs[i][0];
        const float4 x1 = *(const float4*)&xs[i][4];
        const float4 x2 = *(const float4*)&xs[i][8];
        const float4 x3 = *(const float4*)&xs[i][12];
        acc[0]  += (double)x0.x * wd; acc[1]  += (double)x0.y * wd;
        acc[2]  += (double)x0.z * wd; acc[3]  += (double)x0.w * wd;
        acc[4]  += (double)x1.x * wd; acc[5]  += (double)x1.y * wd;
        acc[6]  += (double)x1.z * wd; acc[7]  += (double)x1.w * wd;
        acc[8]  += (double)x2.x * wd; acc[9]  += (double)x2.y * wd;
        acc[10] += (double)x2.z * wd; acc[11] += (double)x2.w * wd;
        acc[12] += (double)x3.x * wd; acc[13] += (double)x3.y * wd;
        acc[14] += (double)x3.z * wd; acc[15] += (double)x3.w * wd;
    }
#pragma unroll
    for (int i = 0; i < NC; ++i) {
        double wd = (double)W1[(NZ + i) * H1 + j];
        const float4 y0 = *(const float4*)&ys[i][0];
        const float4 y1 = *(const float4*)&ys[i][4];
        const float4 y2 = *(const float4*)&ys[i][8];
        const float4 y3 = *(const float4*)&ys[i][12];
        acc[0]  += (double)y0.x * wd; acc[1]  += (double)y0.y * wd;
        acc[2]  += (double)y0.z * wd; acc[3]  += (double)y0.w * wd;
        acc[4]  += (double)y1.x * wd; acc[5]  += (double)y1.y * wd;
        acc[6]  += (double)y1.z * wd; acc[7]  += (double)y1.w * wd;
        acc[8]  += (double)y2.x * wd; acc[9]  += (double)y2.y * wd;
        acc[10] += (double)y2.z * wd; acc[11] += (double)y2.w * wd;
        acc[12] += (double)y3.x * wd; acc[13] += (double)y3.y * wd;
        acc[14] += (double)y3.z * wd; acc[15] += (double)y3.w * wd;
    }
    double bb = (double)b1[j];
    double s = 0.0, s2 = 0.0;
#pragma unroll
    for (int r = 0; r < A1ROWS; ++r) {
        float v = (float)(acc[r] + bb);
        a1[(b0 + r) * H1 + j] = v;
        double dv = (double)v;
        s += dv; s2 += dv * dv;
    }
    p1[blockIdx.x * H1 + j] = s;
    p2[blockIdx.x * H1 + j] = s2;
}

// ---------------------------------------------------------------------------
__global__ __launch_bounds__(256) void k_stats2(
    const double* __restrict__ p1, const double* __restrict__ p2,
    int nprt, int ncol,
    const float* __restrict__ gamma, const float* __restrict__ beta,
    float* __restrict__ scale, float* __restrict__ shift)
{
    const int j = blockIdx.x, t = threadIdx.x;
    double s = 0.0, s2 = 0.0;
    for (int g = t; g < nprt; g += 256) {
        s  += p1[(size_t)g * ncol + j];
        s2 += p2[(size_t)g * ncol + j];
    }
#pragma unroll
    for (int off = 32; off; off >>= 1) {
        s  += __shfl_xor(s, off);
        s2 += __shfl_xor(s2, off);
    }
    __shared__ double ws1[4], ws2[4];
    if ((t & 63) == 0) { ws1[t >> 6] = s; ws2[t >> 6] = s2; }
    __syncthreads();
    if (t == 0) {
        s  = (ws1[0] + ws1[1]) + (ws1[2] + ws1[3]);
        s2 = (ws2[0] + ws2[1]) + (ws2[2] + ws2[3]);
        double mean = s * (1.0 / B_ROWS);
        double var  = s2 * (1.0 / B_ROWS) - mean * mean;
        double rstd = 1.0 / sqrt(var + 1e-5);
        double sc   = (double)gamma[j] * rstd;
        scale[j] = (float)sc;
        shift[j] = (float)((double)beta[j] - mean * sc);
    }
}

// ---------------------------------------------------------------------------
// K3: 16 rows/block; BN1+relu'd h staged once in LDS (padded, float4-aligned);
// thread = 1 col x 4 rows; inner loop = 1 coalesced W2 load + 1 broadcast
// ds_read_b128 + 4 fp64 FMA (was 2 VMEM per 1 FMA -> VMEM-issue-bound).
__global__ __launch_bounds__(256) void k_a2(
    const float* __restrict__ a1,
    const float* __restrict__ sc1, const float* __restrict__ sh1,
    const float* __restrict__ W2, const float* __restrict__ b2,
    float* __restrict__ a2, double* __restrict__ p1, double* __restrict__ p2)
{
    const int t  = threadIdx.x;
    const int k  = t & 63;       // output col
    const int rg = t >> 6;       // row-group (== wave), rows rg*4..rg*4+3
    const int b0 = blockIdx.x * A2ROWS;

    __shared__ __align__(16) float hs[H1][20];   // [j][r], stride 80B (16B-aligned float4 at r%4==0)
    __shared__ double ps[4][64], ps2[4][64];

    {
        const float sct = sc1[t], sht = sh1[t];
#pragma unroll 4
        for (int rr = 0; rr < A2ROWS; ++rr) {
            float v = a1[(size_t)(b0 + rr) * H1 + t];
            hs[t][rr] = fmaxf(fmaf(v, sct, sht), 0.0f);
        }
    }
    __syncthreads();

    const int r0 = rg * 4;
    double acc0 = 0.0, acc1 = 0.0, acc2 = 0.0, acc3 = 0.0;
    for (int j = 0; j < H1; ++j) {
        double wd = (double)W2[j * H2 + k];
        const float4 h4 = *(const float4*)&hs[j][r0];
        acc0 += (double)h4.x * wd;
        acc1 += (double)h4.y * wd;
        acc2 += (double)h4.z * wd;
        acc3 += (double)h4.w * wd;
    }
    const double bb = (double)b2[k];
    float v0 = (float)(acc0 + bb);
    float v1 = (float)(acc1 + bb);
    float v2 = (float)(acc2 + bb);
    float v3 = (float)(acc3 + bb);
    a2[(b0 + r0 + 0) * H2 + k] = v0;
    a2[(b0 + r0 + 1) * H2 + k] = v1;
    a2[(b0 + r0 + 2) * H2 + k] = v2;
    a2[(b0 + r0 + 3) * H2 + k] = v3;

    double s  = (double)v0 + (double)v1 + (double)v2 + (double)v3;
    double s2 = (double)v0 * (double)v0 + (double)v1 * (double)v1
              + (double)v2 * (double)v2 + (double)v3 * (double)v3;
    ps[rg][k] = s; ps2[rg][k] = s2;
    __syncthreads();
    if (t < 64) {
        double S  = (ps[0][t]  + ps[1][t])  + (ps[2][t]  + ps[3][t]);
        double S2 = (ps2[0][t] + ps2[1][t]) + (ps2[2][t] + ps2[3][t]);
        p1[blockIdx.x * H2 + t] = S;
        p2[blockIdx.x * H2 + t] = S2;
    }
}

// ---------------------------------------------------------------------------
// K5: pass A uses SWAPPED MFMA operands (w3 as A, h as B — identical fragment
// layouts) so each lane holds 4 COLS of one ROW: per-tile per-row max is
// 3 in-lane fmax + 2 shfl_xor instead of the 32-VALU DPP reduce.
// Worklist of (row, tile16) cells; pass B = exact fp32, 4 KB/cell.
__global__ __launch_bounds__(512)
__attribute__((amdgpu_waves_per_eu(4, 4)))
void k_main(
    const float* __restrict__ a2,
    const float* __restrict__ sc2, const float* __restrict__ sh2,
    const float* __restrict__ W3, const float* __restrict__ b3,
    const unsigned short* __restrict__ w3s, const float* __restrict__ maxw,
    const float* __restrict__ codebook, float* __restrict__ out)
{
    const int t    = threadIdx.x;
    const int wv   = t >> 6;           // wave 0..7
    const int lane = t & 63;
    const int quad = lane >> 4, col = lane & 15;
    const int b0   = blockIdx.x * RROWS;

    __shared__ __align__(16) float h2T[64][17];     // [j][r], padded
    __shared__ float fineT[NTILE][17];              // per-(tile16, row) bf16 max
    __shared__ float thrS[RROWS];
    __shared__ unsigned long long best[RROWS];
    __shared__ unsigned short wl[RROWS * NTILE];    // sized at true max: no overflow
    __shared__ int wlN;
    __shared__ int rowInd[RROWS];
    __shared__ float maxwS;

    if (t == 0) { maxwS = maxw[0]; wlN = 0; }
    for (int q = t; q < RROWS * 64; q += 512) {
        int j = q >> 4, r = q & 15;
        float v = a2[(b0 + r) * H2 + j];
        h2T[j][r] = fmaxf(fmaf(v, sc2[j], sh2[j]), 0.0f);
    }
    __syncthreads();

    // h fragments (bf16): lane holds h[r=col][k=quad*8+jj], k-halves 0/1
    short8 aF0, aF1;
#pragma unroll
    for (int jj = 0; jj < 8; ++jj) {
        aF0[jj] = (short)f2bf(h2T[quad * 8 + jj][col]);
        aF1[jj] = (short)f2bf(h2T[32 + quad * 8 + jj][col]);
    }

    // ---- Pass A: 8 segments x 8 tiles; swapped-operand MFMA ->
    //      lane holds logit[r=lane&15][c=T*16+quad*4+q] in acc[q] ----
    {
        const uint4*  wp = (const uint4*)w3s + (size_t)wv * 8192 + lane;
        const float4* bq = (const float4*)b3 + wv * 256 + quad;
        for (int s = 0; s < 8; ++s) {
            uint4 c[8], d[8];
            float4 bb[8];
#pragma unroll
            for (int u = 0; u < 8; ++u) {
                c[u]  = wp[u * 128];
                d[u]  = wp[u * 128 + 64];
                bb[u] = bq[u * 4];
            }
#pragma unroll
            for (int u = 0; u < 8; ++u) {
                f32x4 acc = {bb[u].x, bb[u].y, bb[u].z, bb[u].w};
                acc = __builtin_amdgcn_mfma_f32_16x16x32_bf16(
                          *(const short8*)&c[u], aF0, acc, 0, 0, 0);
                acc = __builtin_amdgcn_mfma_f32_16x16x32_bf16(
                          *(const short8*)&d[u], aF1, acc, 0, 0, 0);
                float m = fmaxf(fmaxf(acc[0], acc[1]), fmaxf(acc[2], acc[3]));
                m = fmaxf(m, __shfl_xor(m, 16));
                m = fmaxf(m, __shfl_xor(m, 32));
                if (lane < 16) fineT[(wv * 8 + s) * 8 + u][lane] = m;
            }
            wp += 1024; bq += 32;
        }
    }
    __syncthreads();

    // ---- Thresholds: all 512 threads; row = t>>5, 32 lanes per row ----
    {
        const int r = t >> 5, cc = t & 31;
        float s = fabsf(h2T[2 * cc][r]) + fabsf(h2T[2 * cc + 1][r]);
        float gmv = -1e30f;
#pragma unroll
        for (int k = 0; k < 16; ++k) gmv = fmaxf(gmv, fineT[cc + 32 * k][r]);
#pragma unroll
        for (int off = 1; off < 32; off <<= 1) {
            s   += __shfl_xor(s, off);
            gmv  = fmaxf(gmv, __shfl_xor(gmv, off));
        }
        if (cc == 0) {
            float e = s * maxwS * (1.0f / 256.0f);   // |dlogit| <= S*maxW*2^-8
            thrS[r] = gmv - (0.1068f + e + 1e-3f);
            best[r] = 0ull;
        }
    }
    __syncthreads();

    // ---- Worklist of qualifying (row, tile16) cells ----
    {
        const int r = t >> 5, cc = t & 31;
        const float th = thrS[r];
#pragma unroll
        for (int k = 0; k < 16; ++k) {
            const int T = cc + 32 * k;
            if (fineT[T][r] >= th) {
                int idx = atomicAdd(&wlN, 1);
                wl[idx] = (unsigned short)((r << 9) | T);
            }
        }
    }
    __syncthreads();

    // ---- Pass B: wave handles 4 cells (16 lanes each); exact fp32 ----
    {
        const int n = wlN;
        const int g = lane >> 4;       // cell slot within wave
        for (int i = wv * 4; i < n; i += 32) {
            const int  ci  = i + g;
            const bool act = (ci < n);
            const int  e   = act ? wl[ci] : 0;
            const int  r   = e >> 9;
            const int  T   = e & 511;
            const int  f   = T * 16 + col;
            float acc = b3[f];
            const float* wcol = W3 + f;
#pragma unroll 8
            for (int j = 0; j < 64; ++j) {
                acc = fmaf(h2T[j][r], *wcol, acc);
                wcol += FEATN;
            }
            if (act && acc >= thrS[r]) {
                float sc = acc + gumbel_g((unsigned)(b0 + r) * (unsigned)FEATN + (unsigned)f);
                unsigned long long pk = ((unsigned long long)fmono(sc) << 32)
                                      | (unsigned)(FEATN - 1 - f);
                atomicMax(&best[r], pk);
            }
        }
    }
    __syncthreads();
    if (t < RROWS) {
        rowInd[t] = (FEATN - 1 - (int)(best[t] & 0xFFFFFFFFull)) & (FEATN - 1);
    }
    __syncthreads();

    // ---- out[b,:] = codebook[ind,:] ----
    {
        const int rr = t >> 8, tt = t & 255;
        for (int rp = 0; rp < RROWS / 2; ++rp) {
            const int r = rp * 2 + rr;
            const int ind = rowInd[r];
            const float4* src = (const float4*)(codebook + (size_t)ind * FDIM);
            float4*       dst = (float4*)(out + (size_t)(b0 + r) * FDIM);
            dst[tt] = src[tt];
        }
    }
}

// ---------------------------------------------------------------------------
extern "C" void kernel_launch(void* const* d_in, const int* in_sizes, int n_in,
                              void* d_out, int out_size, void* d_ws, size_t ws_size,
                              hipStream_t stream)
{
    const float* x   = (const float*)d_in[0];
    const float* y   = (const float*)d_in[1];
    const float* W1  = (const float*)d_in[2];
    const float* b1  = (const float*)d_in[3];
    const float* g1  = (const float*)d_in[4];
    const float* be1 = (const float*)d_in[5];
    const float* W2  = (const float*)d_in[6];
    const float* b2  = (const float*)d_in[7];
    const float* g2  = (const float*)d_in[8];
    const float* be2 = (const float*)d_in[9];
    const float* W3  = (const float*)d_in[10];
    const float* b3  = (const float*)d_in[11];
    const float* cb  = (const float*)d_in[12];
    float* out = (float*)d_out;

    float* ws  = (float*)d_ws;
    float* a1  = ws;                          // 8 MB
    float* a2  = a1 + B_ROWS * H1;            // 2 MB
    float* sc1 = a2 + B_ROWS * H2;
    float* sh1 = sc1 + H1;
    float* sc2 = sh1 + H1;
    float* sh2 = sc2 + H2;
    double* p1 = (double*)(sh2 + H2);         // 1 MB
    double* p2 = p1 + A1BLKS * H1;            // 1 MB
    unsigned short* w3s = (unsigned short*)(p2 + A1BLKS * H1);  // 1 MB bf16
    float* maxw = (float*)(w3s + NTILE * 2 * 64 * 8);           // 1 f32

    hipMemsetAsync(maxw, 0, 4, stream);
    k_a1    <<<A1BLKS + CONVBLKS, 256, 0, stream>>>(x, y, W1, b1, W3,
                                                    a1, p1, p2, w3s, maxw);
    k_stats2<<<H1, 256, 0, stream>>>(p1, p2, A1BLKS, H1, g1, be1, sc1, sh1);
    k_a2    <<<A2BLKS, 256, 0, stream>>>(a1, sc1, sh1, W2, b2, a2, p1, p2);
    k_stats2<<<H2, 256, 0, stream>>>(p1, p2, A2BLKS, H2, g2, be2, sc2, sh2);
    k_main  <<<B_ROWS / RROWS, 512, 0, stream>>>(a2, sc2, sh2, W3, b3,
                                                 w3s, maxw, cb, out);
}